// Round 3
// baseline (153.843 us; speedup 1.0000x reference)
//
#include <hip/hip_runtime.h>

// Problem constants (NeighborCooccurrenceEncoder): B=1024, SRC_L=DST_L=256, D=64
#define BATCH 1024
#define L 256
#define D 64
#define NIDS 10000          // ids in [0, 10000)
#define TABN 257            // possible count values 0..256

typedef float f32x4 __attribute__((ext_vector_type(4)));

// ---------------------------------------------------------------------------
// Kernel 1: precompute MLP lookup table.
// tab[a][e] = b2[e] + sum_d relu(a*W1[d] + b1[d]) * W2[e][d],  a in [0,256]
// Rebuilt every launch: d_ws is re-poisoned before each timed call.
// 65 blocks x 256 threads: thread t -> (a = t>>6, e = t&63).
// ---------------------------------------------------------------------------
__global__ __launch_bounds__(256) void build_table_kernel(
        const float* __restrict__ W1,
        const float* __restrict__ b1,
        const float* __restrict__ W2,
        const float* __restrict__ b2,
        float* __restrict__ tab) {
    const int t = blockIdx.x * 256 + threadIdx.x;
    const int a = t >> 6;
    const int e = t & 63;
    if (a >= TABN) return;
    const float af = (float)a;
    float acc = b2[e];
    #pragma unroll
    for (int d = 0; d < D; ++d) {
        float h = fmaf(af, W1[d], b1[d]);   // W1 is (D,1): W1[d][0]
        h = fmaxf(h, 0.0f);
        acc = fmaf(h, W2[e * D + d], acc);
    }
    tab[a * D + e] = acc;
}

// ---------------------------------------------------------------------------
// Kernel 2: per-batch co-occurrence via TWO-PASS 20 KB histogram + table
// gather. One block per batch, 256 threads. LDS = 20 KB hist + 2 KB cnts
// = 22.25 KB -> 7 blocks/CU cap; grid needs 4/CU -> ALL blocks co-resident.
// Histogram is u16-packed by id parity (counts <= 256 fit u16, no carry).
// ---------------------------------------------------------------------------
__global__ __launch_bounds__(256) void cooc_kernel(
        const int* __restrict__ src_ids,
        const int* __restrict__ dst_ids,
        const float* __restrict__ tab,
        float* __restrict__ out) {
    __shared__ alignas(16) unsigned int hist[NIDS / 2];  // 5000 u32 = 20000 B
    __shared__ unsigned int cnts[2 * L];                 // 2048 B

    const int b   = blockIdx.x;
    const int tid = threadIdx.x;

    // each thread owns one src and one dst position (L == blockDim)
    const int sid = src_ids[b * L + tid];
    const int did = dst_ids[b * L + tid];

    uint4* h4 = (uint4*)hist;   // 1250 uint4

    // ---- pass A: histogram of src ids ----
    for (int i = tid; i < NIDS / 8; i += 256) h4[i] = make_uint4(0u, 0u, 0u, 0u);
    __syncthreads();
    atomicAdd(&hist[sid >> 1], 1u << ((sid & 1) * 16));
    __syncthreads();
    unsigned c_ss = (hist[sid >> 1] >> ((sid & 1) * 16)) & 0xffffu; // src_in_src
    unsigned c_ds = (hist[did >> 1] >> ((did & 1) * 16)) & 0xffffu; // dst_in_src
    __syncthreads();   // all reads done before re-zero

    // ---- pass B: histogram of dst ids ----
    for (int i = tid; i < NIDS / 8; i += 256) h4[i] = make_uint4(0u, 0u, 0u, 0u);
    __syncthreads();
    atomicAdd(&hist[did >> 1], 1u << ((did & 1) * 16));
    __syncthreads();
    unsigned c_sd = (hist[sid >> 1] >> ((sid & 1) * 16)) & 0xffffu; // src_in_dst
    unsigned c_dd = (hist[did >> 1] >> ((did & 1) * 16)) & 0xffffu; // dst_in_dst

    // reference zeroes the APPEARANCE features (not the output) for id==0
    if (sid == 0) { c_ss = 0u; c_sd = 0u; }
    if (did == 0) { c_ds = 0u; c_dd = 0u; }
    cnts[tid]     = c_ss | (c_sd << 16);
    cnts[L + tid] = c_ds | (c_dd << 16);
    __syncthreads();

    // ---- phase 4: gather table rows, write output (float4, nontemporal) ----
    // out layout: [src_feat (B,L,D) | dst_feat (B,L,D)], f32
    const f32x4* tab4 = (const f32x4*)tab;
    f32x4*       out4 = (f32x4*)out;
    const int q    = tid & 15;   // float4 slot within 64-float row (D/4 = 16)
    const int pg   = tid >> 4;   // 16 position-groups
    const int ROW4 = D / 4;      // 16

    f32x4* osrc = out4 + (size_t)b * (L * ROW4);
    f32x4* odst = out4 + (size_t)BATCH * L * ROW4 + (size_t)b * (L * ROW4);

    #pragma unroll 4
    for (int p = pg; p < L; p += 16) {
        const unsigned cp = cnts[p];
        const f32x4 v1 = tab4[(cp & 0xffffu) * ROW4 + q];
        const f32x4 v2 = tab4[(cp >> 16) * ROW4 + q];
        __builtin_nontemporal_store(v1 + v2, &osrc[p * ROW4 + q]);
    }
    #pragma unroll 4
    for (int p = pg; p < L; p += 16) {
        const unsigned cp = cnts[L + p];
        const f32x4 v1 = tab4[(cp & 0xffffu) * ROW4 + q];
        const f32x4 v2 = tab4[(cp >> 16) * ROW4 + q];
        __builtin_nontemporal_store(v1 + v2, &odst[p * ROW4 + q]);
    }
}

extern "C" void kernel_launch(void* const* d_in, const int* in_sizes, int n_in,
                              void* d_out, int out_size, void* d_ws, size_t ws_size,
                              hipStream_t stream) {
    const int*   src_ids = (const int*)d_in[0];
    const int*   dst_ids = (const int*)d_in[1];
    const float* W1      = (const float*)d_in[2];
    const float* b1      = (const float*)d_in[3];
    const float* W2      = (const float*)d_in[4];
    const float* b2      = (const float*)d_in[5];
    float*       out     = (float*)d_out;
    float*       tab     = (float*)d_ws;   // 257*64*4 = 65,792 B

    build_table_kernel<<<(TABN * 64 + 255) / 256, 256, 0, stream>>>(W1, b1, W2, b2, tab);
    cooc_kernel<<<BATCH, 256, 0, stream>>>(src_ids, dst_ids, tab, out);
}

// Round 4
// 153.405 us; speedup vs baseline: 1.0029x; 1.0029x over previous
//
#include <hip/hip_runtime.h>

// Problem constants (NeighborCooccurrenceEncoder): B=1024, SRC_L=DST_L=256, D=64
#define BATCH 1024
#define L 256
#define D 64
#define NIDS 10000          // ids in [0, 10000)
#define TABN 257            // possible count values 0..256

typedef float f32x4 __attribute__((ext_vector_type(4)));

// ---------------------------------------------------------------------------
// Kernel 1: precompute MLP lookup table.
// tab[a][e] = b2[e] + sum_d relu(a*W1[d] + b1[d]) * W2[e][d],  a in [0,256]
// Rebuilt every launch: d_ws is re-poisoned before each timed call.
// ---------------------------------------------------------------------------
__global__ __launch_bounds__(256) void build_table_kernel(
        const float* __restrict__ W1,
        const float* __restrict__ b1,
        const float* __restrict__ W2,
        const float* __restrict__ b2,
        float* __restrict__ tab) {
    const int t = blockIdx.x * 256 + threadIdx.x;
    const int a = t >> 6;
    const int e = t & 63;
    if (a >= TABN) return;
    const float af = (float)a;
    float acc = b2[e];
    #pragma unroll
    for (int d = 0; d < D; ++d) {
        float h = fmaf(af, W1[d], b1[d]);   // W1 is (D,1): W1[d][0]
        h = fmaxf(h, 0.0f);
        acc = fmaf(h, W2[e * D + d], acc);
    }
    tab[a * D + e] = acc;
}

// ---------------------------------------------------------------------------
// Kernel 2: 2048 blocks — block (b, half): half 0 writes src_feat[b],
// half 1 writes dst_feat[b]. LDS = exactly 20 KiB (hist reused for cnts)
// -> 8 blocks/CU, 32 waves/CU, ALL blocks co-resident.
//
// Single zero pass + subtraction trick:
//   zero; add src ids; r1 = hist[myid]      (= count of myid in src)
//   barrier; add dst ids ON TOP; r2 = hist[myid] (= src_cnt + dst_cnt)
//   counts = (r1, r2 - r1).  u16 halves hold <= 512: no carry, exact.
// ---------------------------------------------------------------------------
__global__ __launch_bounds__(256, 8) void cooc_kernel(
        const int* __restrict__ src_ids,
        const int* __restrict__ dst_ids,
        const float* __restrict__ tab,
        float* __restrict__ out) {
    __shared__ alignas(16) unsigned int hist[NIDS / 2];  // 5000 u32 = 20000 B

    const int bid  = blockIdx.x;
    const int b    = bid >> 1;
    const int half = bid & 1;
    const int tid  = threadIdx.x;

    const int sid  = src_ids[b * L + tid];
    const int did  = dst_ids[b * L + tid];
    const int myid = half ? did : sid;

    // zero histogram (1250 uint4)
    uint4* h4 = (uint4*)hist;
    #pragma unroll
    for (int i = tid; i < NIDS / 8; i += 256) h4[i] = make_uint4(0u, 0u, 0u, 0u);
    __syncthreads();

    // pass A: histogram src ids
    atomicAdd(&hist[sid >> 1], 1u << ((sid & 1) * 16));
    __syncthreads();
    const unsigned r1 = (hist[myid >> 1] >> ((myid & 1) * 16)) & 0xffffu;
    __syncthreads();   // r1 reads complete before pass-B atomics touch hist

    // pass B: histogram dst ids ON TOP
    atomicAdd(&hist[did >> 1], 1u << ((did & 1) * 16));
    __syncthreads();
    const unsigned r2 = (hist[myid >> 1] >> ((myid & 1) * 16)) & 0xffffu;

    unsigned c1 = r1;        // count of myid in src
    unsigned c2 = r2 - r1;   // count of myid in dst
    if (myid == 0) { c1 = 0u; c2 = 0u; }   // reference masks id==0 appearances
    __syncthreads();   // all r2 reads done before hist reuse

    // reuse hist[0..255] as per-position packed counts
    hist[tid] = c1 | (c2 << 16);
    __syncthreads();

    // write 256 rows x 64 f32 (64 KiB), float4-vectorized, nontemporal.
    // wave writes 4 contiguous rows (1 KiB) per iteration.
    const f32x4* tab4 = (const f32x4*)tab;
    f32x4* o = (f32x4*)out + (size_t)(half * BATCH + b) * (L * 16);
    const int q  = tid & 15;
    const int pg = tid >> 4;

    #pragma unroll 4
    for (int k = 0; k < 16; ++k) {
        const int p = pg + 16 * k;
        const unsigned cp = hist[p];
        const f32x4 v1 = tab4[(cp & 0xffffu) * 16 + q];
        const f32x4 v2 = tab4[(cp >> 16) * 16 + q];
        __builtin_nontemporal_store(v1 + v2, &o[p * 16 + q]);
    }
}

extern "C" void kernel_launch(void* const* d_in, const int* in_sizes, int n_in,
                              void* d_out, int out_size, void* d_ws, size_t ws_size,
                              hipStream_t stream) {
    const int*   src_ids = (const int*)d_in[0];
    const int*   dst_ids = (const int*)d_in[1];
    const float* W1      = (const float*)d_in[2];
    const float* b1      = (const float*)d_in[3];
    const float* W2      = (const float*)d_in[4];
    const float* b2      = (const float*)d_in[5];
    float*       out     = (float*)d_out;
    float*       tab     = (float*)d_ws;   // 257*64*4 = 65,792 B

    build_table_kernel<<<(TABN * 64 + 255) / 256, 256, 0, stream>>>(W1, b1, W2, b2, tab);
    cooc_kernel<<<2 * BATCH, 256, 0, stream>>>(src_ids, dst_ids, tab, out);
}